// Round 8
// baseline (140.613 us; speedup 1.0000x reference)
//
#include <hip/hip_runtime.h>

typedef __attribute__((ext_vector_type(8))) short short8;
typedef __attribute__((ext_vector_type(4))) float floatx4;

static __device__ __forceinline__ unsigned short f2bf(float f) {
    unsigned u = __float_as_uint(f);
    u += 0x7FFFu + ((u >> 16) & 1u);
    return (unsigned short)(u >> 16);
}

// ================= single fused kernel =================
// R8: same body as R7 (zero-LDS H path), geometry pushed to the HW
// occupancy max: 1024-thread blocks (16 waves), 2 blocks/CU ->
// 32 waves/CU = 8 waves/SIMD. This works NOW because R7's body measured
// 64 VGPRs with zero spill (WRITE == output exactly), so the 64-reg
// budget of 8-waves/SIMD is a fit, not a spill trigger (R5's 1024-thread
// failure was the old 116-reg sH body). LDS 2 x 66560B = 133KB <= 160KB
// with 27KB margin (R2 proved 144KB co-resides; R4 failed only at the
// exact 160KB boundary). Threads 2x1024 = 2048 = maxThreadsPerCU, exact.
//
// R7 recap (unchanged): GEMM1 swaps MFMA operands (mfma(wb, a)) so each
// lane accumulates H for ITS OWN sample; the h-dimension is globally
// permuted at staging (slot(h) = (2*(h>>5)+((h>>2)&1))*16 +
// ((h>>3)&3)*4 + (h&3), applied to W1 rows + b1; W2 read in logical-h
// order), making the packed GEMM1 outputs concatenate into EXACTLY the
// K=32 GEMM2 A-fragment: zero cross-lane, zero LDS H traffic, no
// __syncthreads in the tile loop. b1 folded into MFMA C-init, b2 into
// oacc init. Pack via v_cvt_pk_bf16_f32 (RNE = f2bf).
//
// Lane mapping (R2): lane (q,l16) of wave w owns sample w*16+l16 with
// coord chunks {8q..8q+7} and {32+8q..+7}; quad reduction = shfl_xor
// 16/32; post-solve bf16 values ARE the GEMM1 B-frags a0/a1; e^s fans
// out with 4 __shfl. Newton: log-Newton on G=ln F in base 2
// (s += log2(v)*v/dv2), init = step from s=0; wave-uniform early break
// __all(|v-1|<1e-5). The -1 of F applies ONCE, post-reduction.
__global__ __launch_bounds__(1024, 2) void fused_k(const float* __restrict__ x,
                                                   const float* __restrict__ r,
                                                   const float* __restrict__ W1f,
                                                   const float* __restrict__ b1,
                                                   const float* __restrict__ W2f,
                                                   const float* __restrict__ b2,
                                                   float* __restrict__ out,
                                                   int tiles_per_block) {
    __shared__ unsigned short sW1[256 * 64];  // 32 KB, PERMUTED rows, swizzled
    __shared__ unsigned short sW2[64 * 256];  // 32 KB, logical-h order, swizzled
    __shared__ float sB1[256];                //  1 KB, b1 at permuted slots

    int tid = threadIdx.x;

    // ---- stage W1 [256x64] fp32 -> bf16, row-PERMUTED by pi, swizzled
    const float4* w1f4 = (const float4*)W1f;
#pragma unroll
    for (int c = 0; c < 2; ++c) {
        int g = tid + c * 1024;
        int h = g >> 3, ch = g & 7;  // logical row, 8-elem chunk
        int prow = ((h >> 5) * 2 + ((h >> 2) & 1)) * 16 + ((h >> 3) & 3) * 4 + (h & 3);
        float4 lo = w1f4[2 * g], hi = w1f4[2 * g + 1];
        uint4 p;
        p.x = (unsigned)f2bf(lo.x) | ((unsigned)f2bf(lo.y) << 16);
        p.y = (unsigned)f2bf(lo.z) | ((unsigned)f2bf(lo.w) << 16);
        p.z = (unsigned)f2bf(hi.x) | ((unsigned)f2bf(hi.y) << 16);
        p.w = (unsigned)f2bf(hi.z) | ((unsigned)f2bf(hi.w) << 16);
        *(uint4*)&sW1[prow * 64 + (ch ^ (prow & 7)) * 8] = p;
    }
    // ---- stage W2 [64x256] fp32 -> bf16 swizzled (logical h order)
    const float4* w2f4 = (const float4*)W2f;
#pragma unroll
    for (int c = 0; c < 2; ++c) {
        int g = tid + c * 1024;
        float4 lo = w2f4[2 * g], hi = w2f4[2 * g + 1];
        uint4 p;
        p.x = (unsigned)f2bf(lo.x) | ((unsigned)f2bf(lo.y) << 16);
        p.y = (unsigned)f2bf(lo.z) | ((unsigned)f2bf(lo.w) << 16);
        p.z = (unsigned)f2bf(hi.x) | ((unsigned)f2bf(hi.y) << 16);
        p.w = (unsigned)f2bf(hi.z) | ((unsigned)f2bf(hi.w) << 16);
        int row = g >> 5, ch = g & 31;
        *(uint4*)&sW2[row * 256 + (ch ^ (row & 7)) * 8] = p;
    }
    // ---- stage b1 at permuted slots
    if (tid < 256) {
        int h = tid;
        int prow = ((h >> 5) * 2 + ((h >> 2) & 1)) * 16 + ((h >> 3) & 3) * 4 + (h & 3);
        sB1[prow] = b1[h];
    }
    __syncthreads();

    int wave = tid >> 6, lane = tid & 63;  // wave 0..15
    int q = lane >> 4, l16 = lane & 15;
    int sx = l16 & 7;  // swizzle key for rows indexed by l16

    float bias2[4];
#pragma unroll
    for (int n = 0; n < 4; ++n) bias2[n] = b2[n * 16 + l16];

    // ---- per-thread rate chunks: coords {8q..8q+7} and {32+8q..+7}
    const float L2E2 = 2.8853900817779268f;  // 2*log2(e)
    float rl2[16];
    {
        const float4* r4 = (const float4*)r;
        float4 ra = r4[2 * q], rb = r4[2 * q + 1];
        float4 rc = r4[8 + 2 * q], rd = r4[8 + 2 * q + 1];
        rl2[0] = ra.x * L2E2; rl2[1] = ra.y * L2E2; rl2[2] = ra.z * L2E2; rl2[3] = ra.w * L2E2;
        rl2[4] = rb.x * L2E2; rl2[5] = rb.y * L2E2; rl2[6] = rb.z * L2E2; rl2[7] = rb.w * L2E2;
        rl2[8] = rc.x * L2E2; rl2[9] = rc.y * L2E2; rl2[10] = rc.z * L2E2; rl2[11] = rc.w * L2E2;
        rl2[12] = rd.x * L2E2; rl2[13] = rd.y * L2E2; rl2[14] = rd.z * L2E2; rl2[15] = rd.w * L2E2;
    }

    for (int tt = 0; tt < tiles_per_block; ++tt) {
        size_t m0 = ((size_t)blockIdx.x * tiles_per_block + tt) * 256;
        int myrow = wave * 16 + l16;  // 0..255

        // ---- load this thread's x chunks (sample myrow, coords 8q.. / 32+8q..)
        const float4* x4 = (const float4*)(x + (m0 + myrow) * 64);
        float4 va = x4[2 * q], vb = x4[2 * q + 1];
        float4 vc = x4[8 + 2 * q], vd = x4[8 + 2 * q + 1];
        float xv[16];
        xv[0] = va.x; xv[1] = va.y; xv[2] = va.z; xv[3] = va.w;
        xv[4] = vb.x; xv[5] = vb.y; xv[6] = vb.z; xv[7] = vb.w;
        xv[8] = vc.x; xv[9] = vc.y; xv[10] = vc.z; xv[11] = vc.w;
        xv[12] = vd.x; xv[13] = vd.y; xv[14] = vd.z; xv[15] = vd.w;

        float x2[16], rx2[16];
        float sum0 = 0.f, sumr = 0.f;
        int nz = 0;
#pragma unroll
        for (int j = 0; j < 16; ++j) {
            x2[j] = xv[j] * xv[j];
            rx2[j] = rl2[j] * x2[j];
            sum0 += x2[j];
            sumr += rx2[j];
            nz |= (fabsf(xv[j]) > 1e-12f) ? 1 : 0;
        }
        // quad reduction: the 4 owners of a sample differ in lane bits 4,5
        sum0 += __shfl_xor(sum0, 16); sum0 += __shfl_xor(sum0, 32);
        sumr += __shfl_xor(sumr, 16); sumr += __shfl_xor(sumr, 32);
        nz   |= __shfl_xor(nz, 16);   nz   |= __shfl_xor(nz, 32);

        float s = 0.f;
        if (nz) {
            // init = log-Newton step from s=0
            s = __log2f(sum0) * sum0 * __builtin_amdgcn_rcpf(sumr);
#pragma unroll 1
            for (int it = 0; it < 10; ++it) {
                float ns = -s;
                float v = 0.f, dv = 0.f;
#pragma unroll
                for (int j = 0; j < 16; ++j) {
                    float e = __builtin_amdgcn_exp2f(ns * rl2[j]);
                    v = fmaf(e, x2[j], v);
                    dv = fmaf(e, rx2[j], dv);
                }
                v += __shfl_xor(v, 16);   v += __shfl_xor(v, 32);
                dv += __shfl_xor(dv, 16); dv += __shfl_xor(dv, 32);
                if (__all(fabsf(v - 1.f) < 1e-5f)) break;
                // log-Newton in base 2: s += log2(v)*v/dv2
                s += __log2f(v) * v * __builtin_amdgcn_rcpf(dv);
            }
        }

        // ---- B-frags (GEMM1) directly from the solve: xs = x * 2^{-s*rl2/2}
        float hs = -0.5f * s;
        short8 a0, a1;
#pragma unroll
        for (int j = 0; j < 8; ++j)
            a0[j] = (short)f2bf(xv[j] * __builtin_amdgcn_exp2f(hs * rl2[j]));
#pragma unroll
        for (int j = 0; j < 8; ++j)
            a1[j] = (short)f2bf(xv[8 + j] * __builtin_amdgcn_exp2f(hs * rl2[8 + j]));

        // e^s, fan out to the lanes that scale samples q*4+reg
        float es = __builtin_amdgcn_exp2f(s * 1.4426950408889634f);
        float sc[4];
#pragma unroll
        for (int reg = 0; reg < 4; ++reg) sc[reg] = __shfl(es, q * 4 + reg);

        floatx4 oacc[4];
#pragma unroll
        for (int n = 0; n < 4; ++n)
            oacc[n] = (floatx4){bias2[n], bias2[n], bias2[n], bias2[n]};

#pragma unroll
        for (int hc = 0; hc < 8; ++hc) {
            // ---- GEMM1 (swapped), subtile pair (2hc, 2hc+1):
            // acc[reg] = H[logical h = hc*32 + q*8 + p*4 + reg][sample l16]
            unsigned pk0, pk1, pk2, pk3;
            {
                int t = hc * 2;
                int row = t * 16 + l16;
                short8 wb0 = *(const short8*)&sW1[row * 64 + (q ^ sx) * 8];
                short8 wb1 = *(const short8*)&sW1[row * 64 + ((q + 4) ^ sx) * 8];
                const float4 bb = *(const float4*)&sB1[t * 16 + q * 4];
                floatx4 acc = (floatx4){bb.x, bb.y, bb.z, bb.w};
                acc = __builtin_amdgcn_mfma_f32_16x16x32_bf16(wb0, a0, acc, 0, 0, 0);
                acc = __builtin_amdgcn_mfma_f32_16x16x32_bf16(wb1, a1, acc, 0, 0, 0);
                float h0 = fmaxf(acc[0], 0.f), h1 = fmaxf(acc[1], 0.f);
                float h2 = fmaxf(acc[2], 0.f), h3 = fmaxf(acc[3], 0.f);
                asm("v_cvt_pk_bf16_f32 %0, %1, %2" : "=v"(pk0) : "v"(h0), "v"(h1));
                asm("v_cvt_pk_bf16_f32 %0, %1, %2" : "=v"(pk1) : "v"(h2), "v"(h3));
            }
            {
                int t = hc * 2 + 1;
                int row = t * 16 + l16;
                short8 wb0 = *(const short8*)&sW1[row * 64 + (q ^ sx) * 8];
                short8 wb1 = *(const short8*)&sW1[row * 64 + ((q + 4) ^ sx) * 8];
                const float4 bb = *(const float4*)&sB1[t * 16 + q * 4];
                floatx4 acc = (floatx4){bb.x, bb.y, bb.z, bb.w};
                acc = __builtin_amdgcn_mfma_f32_16x16x32_bf16(wb0, a0, acc, 0, 0, 0);
                acc = __builtin_amdgcn_mfma_f32_16x16x32_bf16(wb1, a1, acc, 0, 0, 0);
                float h0 = fmaxf(acc[0], 0.f), h1 = fmaxf(acc[1], 0.f);
                float h2 = fmaxf(acc[2], 0.f), h3 = fmaxf(acc[3], 0.f);
                asm("v_cvt_pk_bf16_f32 %0, %1, %2" : "=v"(pk2) : "v"(h0), "v"(h1));
                asm("v_cvt_pk_bf16_f32 %0, %1, %2" : "=v"(pk3) : "v"(h2), "v"(h3));
            }
            // ---- A-frag for GEMM2 K-chunk hc: ha[j] = H[sample l16][hc*32+q*8+j]
            int4 hw = make_int4((int)pk0, (int)pk1, (int)pk2, (int)pk3);
            short8 ha = *(short8*)&hw;
#pragma unroll
            for (int n = 0; n < 4; ++n) {
                int orow = n * 16 + l16;  // W2 row = o index
                short8 wb = *(const short8*)&sW2[orow * 256 + ((hc * 4 + q) ^ sx) * 8];
                oacc[n] = __builtin_amdgcn_mfma_f32_16x16x32_bf16(ha, wb, oacc[n], 0, 0, 0);
            }
        }
        // ---- epilogue: out = (H @ W2^T + b2) * e^s   (b2 folded into init)
#pragma unroll
        for (int n = 0; n < 4; ++n) {
#pragma unroll
            for (int reg = 0; reg < 4; ++reg) {
                out[(m0 + wave * 16 + q * 4 + reg) * 64 + n * 16 + l16] =
                    oacc[n][reg] * sc[reg];
            }
        }
    }
}

extern "C" void kernel_launch(void* const* d_in, const int* in_sizes, int n_in,
                              void* d_out, int out_size, void* d_ws, size_t ws_size,
                              hipStream_t stream) {
    const float* x  = (const float*)d_in[0];
    const float* r  = (const float*)d_in[1];
    const float* W1 = (const float*)d_in[2];
    const float* b1 = (const float*)d_in[3];
    const float* W2 = (const float*)d_in[4];
    const float* b2 = (const float*)d_in[5];
    float* out = (float*)d_out;
    int B = in_sizes[0] / 64;  // 262144

    int tiles = B / 256;           // 1024 tiles of 256 samples
    int blocks = 512;              // 2 per CU
    int tpb = tiles / blocks;      // 2

    fused_k<<<blocks, 1024, 0, stream>>>(x, r, W1, b1, W2, b2, out, tpb);
}

// Round 9
// 140.524 us; speedup vs baseline: 1.0006x; 1.0006x over previous
//
#include <hip/hip_runtime.h>

typedef __attribute__((ext_vector_type(8))) short short8;
typedef __attribute__((ext_vector_type(4))) float floatx4;

static __device__ __forceinline__ unsigned short f2bf(float f) {
    unsigned u = __float_as_uint(f);
    u += 0x7FFFu + ((u >> 16) & 1u);
    return (unsigned short)(u >> 16);
}

// ================= single fused kernel =================
// R9: issue-count diet on the R7 structure. R8 proved occupancy is NOT
// the lever (4 vs 8 waves/SIMD identical) -> the bound is shared VALU+DS
// issue (~24us VALU busy + ~22us LDS-pipe busy at ~50us dur). Cuts:
//  1. HALLEY (3rd-order) solve: +d2=sum(e*r^2x^2) chain per iter, cuts
//     ~1.5 evals of (16 trans + 48 fma + ~350cy serial). Correction
//     corr = 1/(1-t), t = 0.5*ln(v)*(d2*v/dv^2 - 1) clamped <= 0.7
//     (t>=0 for v>1 by Cauchy-Schwarz; t<0 damps when v<1 -- safe).
//  2. a0/a1 packed via v_cvt_pk_bf16_f32 (RNE, proven here for H):
//     8 cvt_pk replace 16x 3-op f2bf (-40 VALU).
//  3. Next-tile x PREFETCH: tile tt+1's 4 float4 loads issued right
//     after tt's unpack -> L3-hit latency (~300-500cy) leaves the
//     serial chain head (compiler can't pipeline across the
//     early-break loop itself).
// Geometry = R7 (best measured): 512 threads, LDS 66560B -> 2 blocks/CU,
// 16 waves/CU. __launch_bounds__(512,2) -> 128-reg cap; body now ~110
// regs (r2x2 + prefetch), no spill (R4 precedent at 116).
//
// R7 recap (unchanged): GEMM1 swapped (mfma(wb,a)) so each lane holds H
// for its own sample; h-dimension globally permuted at staging (slot(h)
// applied to W1 rows + b1; W2 read logical) so packed GEMM1 outputs
// concatenate into EXACTLY the K=32 GEMM2 A-frag; zero LDS H traffic,
// no __syncthreads in tile loop; b1 in MFMA C-init, b2 in oacc init.
// Lane mapping (R2): lane (q,l16) of wave w owns sample w*16+l16, coord
// chunks {8q..8q+7} / {32+8q..+7}; quad reduction = shfl_xor 16/32;
// e^s fans out with 4 __shfl. Early break __all(|v-1|<1e-5); the -1 of
// F applies ONCE, post-reduction.
__global__ __launch_bounds__(512, 2) void fused_k(const float* __restrict__ x,
                                                  const float* __restrict__ r,
                                                  const float* __restrict__ W1f,
                                                  const float* __restrict__ b1,
                                                  const float* __restrict__ W2f,
                                                  const float* __restrict__ b2,
                                                  float* __restrict__ out,
                                                  int tiles_per_block) {
    __shared__ unsigned short sW1[256 * 64];  // 32 KB, PERMUTED rows, swizzled
    __shared__ unsigned short sW2[64 * 256];  // 32 KB, logical-h order, swizzled
    __shared__ float sB1[256];                //  1 KB, b1 at permuted slots

    int tid = threadIdx.x;

    // ---- stage W1 [256x64] fp32 -> bf16, row-PERMUTED by pi, swizzled
    const float4* w1f4 = (const float4*)W1f;
#pragma unroll
    for (int c = 0; c < 4; ++c) {
        int g = tid + c * 512;
        int h = g >> 3, ch = g & 7;  // logical row, 8-elem chunk
        int prow = ((h >> 5) * 2 + ((h >> 2) & 1)) * 16 + ((h >> 3) & 3) * 4 + (h & 3);
        float4 lo = w1f4[2 * g], hi = w1f4[2 * g + 1];
        uint4 p;
        p.x = (unsigned)f2bf(lo.x) | ((unsigned)f2bf(lo.y) << 16);
        p.y = (unsigned)f2bf(lo.z) | ((unsigned)f2bf(lo.w) << 16);
        p.z = (unsigned)f2bf(hi.x) | ((unsigned)f2bf(hi.y) << 16);
        p.w = (unsigned)f2bf(hi.z) | ((unsigned)f2bf(hi.w) << 16);
        *(uint4*)&sW1[prow * 64 + (ch ^ (prow & 7)) * 8] = p;
    }
    // ---- stage W2 [64x256] fp32 -> bf16 swizzled (logical h order)
    const float4* w2f4 = (const float4*)W2f;
#pragma unroll
    for (int c = 0; c < 4; ++c) {
        int g = tid + c * 512;
        float4 lo = w2f4[2 * g], hi = w2f4[2 * g + 1];
        uint4 p;
        p.x = (unsigned)f2bf(lo.x) | ((unsigned)f2bf(lo.y) << 16);
        p.y = (unsigned)f2bf(lo.z) | ((unsigned)f2bf(lo.w) << 16);
        p.z = (unsigned)f2bf(hi.x) | ((unsigned)f2bf(hi.y) << 16);
        p.w = (unsigned)f2bf(hi.z) | ((unsigned)f2bf(hi.w) << 16);
        int row = g >> 5, ch = g & 31;
        *(uint4*)&sW2[row * 256 + (ch ^ (row & 7)) * 8] = p;
    }
    // ---- stage b1 at permuted slots
    if (tid < 256) {
        int h = tid;
        int prow = ((h >> 5) * 2 + ((h >> 2) & 1)) * 16 + ((h >> 3) & 3) * 4 + (h & 3);
        sB1[prow] = b1[h];
    }
    __syncthreads();

    int wave = tid >> 6, lane = tid & 63;
    int q = lane >> 4, l16 = lane & 15;
    int sx = l16 & 7;  // swizzle key for rows indexed by l16

    float bias2[4];
#pragma unroll
    for (int n = 0; n < 4; ++n) bias2[n] = b2[n * 16 + l16];

    // ---- per-thread rate chunks: coords {8q..8q+7} and {32+8q..+7}
    const float L2E2 = 2.8853900817779268f;  // 2*log2(e)
    float rl2[16];
    {
        const float4* r4 = (const float4*)r;
        float4 ra = r4[2 * q], rb = r4[2 * q + 1];
        float4 rc = r4[8 + 2 * q], rd = r4[8 + 2 * q + 1];
        rl2[0] = ra.x * L2E2; rl2[1] = ra.y * L2E2; rl2[2] = ra.z * L2E2; rl2[3] = ra.w * L2E2;
        rl2[4] = rb.x * L2E2; rl2[5] = rb.y * L2E2; rl2[6] = rb.z * L2E2; rl2[7] = rb.w * L2E2;
        rl2[8] = rc.x * L2E2; rl2[9] = rc.y * L2E2; rl2[10] = rc.z * L2E2; rl2[11] = rc.w * L2E2;
        rl2[12] = rd.x * L2E2; rl2[13] = rd.y * L2E2; rl2[14] = rd.z * L2E2; rl2[15] = rd.w * L2E2;
    }

    int myrow = wave * 16 + l16;  // 0..127
    size_t mb = (size_t)blockIdx.x * tiles_per_block * 128;
    const float4* xt = (const float4*)(x + (mb + myrow) * 64);  // tile 0, my row

    // ---- prefetch tile 0
    float4 va = xt[2 * q], vb = xt[2 * q + 1];
    float4 vc = xt[8 + 2 * q], vd = xt[8 + 2 * q + 1];

    for (int tt = 0; tt < tiles_per_block; ++tt) {
        size_t m0 = mb + (size_t)tt * 128;

        float xv[16];
        xv[0] = va.x; xv[1] = va.y; xv[2] = va.z; xv[3] = va.w;
        xv[4] = vb.x; xv[5] = vb.y; xv[6] = vb.z; xv[7] = vb.w;
        xv[8] = vc.x; xv[9] = vc.y; xv[10] = vc.z; xv[11] = vc.w;
        xv[12] = vd.x; xv[13] = vd.y; xv[14] = vd.z; xv[15] = vd.w;

        // ---- issue next tile's loads NOW (hide L3/HBM latency under solve+GEMM)
        {
            int nt = (tt + 1 < tiles_per_block) ? (tt + 1) : tt;
            const float4* xn = xt + (size_t)nt * 2048;  // 128 rows * 16 float4
            va = xn[2 * q]; vb = xn[2 * q + 1];
            vc = xn[8 + 2 * q]; vd = xn[8 + 2 * q + 1];
        }

        float x2[16], rx2[16], r2x2[16];
        float sum0 = 0.f, sumr = 0.f;
        int nz = 0;
#pragma unroll
        for (int j = 0; j < 16; ++j) {
            x2[j] = xv[j] * xv[j];
            rx2[j] = rl2[j] * x2[j];
            r2x2[j] = rl2[j] * rx2[j];
            sum0 += x2[j];
            sumr += rx2[j];
            nz |= (fabsf(xv[j]) > 1e-12f) ? 1 : 0;
        }
        // quad reduction: the 4 owners of a sample differ in lane bits 4,5
        sum0 += __shfl_xor(sum0, 16); sum0 += __shfl_xor(sum0, 32);
        sumr += __shfl_xor(sumr, 16); sumr += __shfl_xor(sumr, 32);
        nz   |= __shfl_xor(nz, 16);   nz   |= __shfl_xor(nz, 32);

        float s = 0.f;
        if (nz) {
            // init = log-Newton step from s=0
            s = __log2f(sum0) * sum0 * __builtin_amdgcn_rcpf(sumr);
#pragma unroll 1
            for (int it = 0; it < 8; ++it) {
                float ns = -s;
                float v = 0.f, dv = 0.f, d2 = 0.f;
#pragma unroll
                for (int j = 0; j < 16; ++j) {
                    float e = __builtin_amdgcn_exp2f(ns * rl2[j]);
                    v  = fmaf(e, x2[j], v);
                    dv = fmaf(e, rx2[j], dv);
                    d2 = fmaf(e, r2x2[j], d2);
                }
                v  += __shfl_xor(v, 16);  v  += __shfl_xor(v, 32);
                dv += __shfl_xor(dv, 16); dv += __shfl_xor(dv, 32);
                d2 += __shfl_xor(d2, 16); d2 += __shfl_xor(d2, 32);
                if (__all(fabsf(v - 1.f) < 1e-5f)) break;
                // Halley on G=log2 F: s += log2(v)*v/dv * 1/(1 - t),
                // t = 0.5*ln(v)*(d2*v/dv^2 - 1), clamped <= 0.7
                float l2v = __log2f(v);
                float rdv = __builtin_amdgcn_rcpf(dv);
                float tcor = (0.34657359f * l2v) * fmaf(d2 * v, rdv * rdv, -1.f);
                tcor = fminf(tcor, 0.7f);
                s += l2v * v * rdv * __builtin_amdgcn_rcpf(1.f - tcor);
            }
        }

        // ---- B-frags (GEMM1) from the solve: xs = x * 2^{-s*rl2/2}, packed
        float hs = -0.5f * s;
        unsigned pa[8];
#pragma unroll
        for (int j = 0; j < 8; ++j) {
            float ea = xv[2 * j] * __builtin_amdgcn_exp2f(hs * rl2[2 * j]);
            float eb = xv[2 * j + 1] * __builtin_amdgcn_exp2f(hs * rl2[2 * j + 1]);
            asm("v_cvt_pk_bf16_f32 %0, %1, %2" : "=v"(pa[j]) : "v"(ea), "v"(eb));
        }
        int4 w0 = make_int4((int)pa[0], (int)pa[1], (int)pa[2], (int)pa[3]);
        int4 w1 = make_int4((int)pa[4], (int)pa[5], (int)pa[6], (int)pa[7]);
        short8 a0 = *(short8*)&w0;
        short8 a1 = *(short8*)&w1;

        // e^s, fan out to the lanes that scale samples q*4+reg
        float es = __builtin_amdgcn_exp2f(s * 1.4426950408889634f);
        float sc[4];
#pragma unroll
        for (int reg = 0; reg < 4; ++reg) sc[reg] = __shfl(es, q * 4 + reg);

        floatx4 oacc[4];
#pragma unroll
        for (int n = 0; n < 4; ++n)
            oacc[n] = (floatx4){bias2[n], bias2[n], bias2[n], bias2[n]};

#pragma unroll
        for (int hc = 0; hc < 8; ++hc) {
            // ---- GEMM1 (swapped), subtile pair (2hc, 2hc+1):
            // acc[reg] = H[logical h = hc*32 + q*8 + p*4 + reg][sample l16]
            unsigned pk0, pk1, pk2, pk3;
            {
                int t = hc * 2;
                int row = t * 16 + l16;
                short8 wb0 = *(const short8*)&sW1[row * 64 + (q ^ sx) * 8];
                short8 wb1 = *(const short8*)&sW1[row * 64 + ((q + 4) ^ sx) * 8];
                const float4 bb = *(const float4*)&sB1[t * 16 + q * 4];
                floatx4 acc = (floatx4){bb.x, bb.y, bb.z, bb.w};
                acc = __builtin_amdgcn_mfma_f32_16x16x32_bf16(wb0, a0, acc, 0, 0, 0);
                acc = __builtin_amdgcn_mfma_f32_16x16x32_bf16(wb1, a1, acc, 0, 0, 0);
                float h0 = fmaxf(acc[0], 0.f), h1 = fmaxf(acc[1], 0.f);
                float h2 = fmaxf(acc[2], 0.f), h3 = fmaxf(acc[3], 0.f);
                asm("v_cvt_pk_bf16_f32 %0, %1, %2" : "=v"(pk0) : "v"(h0), "v"(h1));
                asm("v_cvt_pk_bf16_f32 %0, %1, %2" : "=v"(pk1) : "v"(h2), "v"(h3));
            }
            {
                int t = hc * 2 + 1;
                int row = t * 16 + l16;
                short8 wb0 = *(const short8*)&sW1[row * 64 + (q ^ sx) * 8];
                short8 wb1 = *(const short8*)&sW1[row * 64 + ((q + 4) ^ sx) * 8];
                const float4 bb = *(const float4*)&sB1[t * 16 + q * 4];
                floatx4 acc = (floatx4){bb.x, bb.y, bb.z, bb.w};
                acc = __builtin_amdgcn_mfma_f32_16x16x32_bf16(wb0, a0, acc, 0, 0, 0);
                acc = __builtin_amdgcn_mfma_f32_16x16x32_bf16(wb1, a1, acc, 0, 0, 0);
                float h0 = fmaxf(acc[0], 0.f), h1 = fmaxf(acc[1], 0.f);
                float h2 = fmaxf(acc[2], 0.f), h3 = fmaxf(acc[3], 0.f);
                asm("v_cvt_pk_bf16_f32 %0, %1, %2" : "=v"(pk2) : "v"(h0), "v"(h1));
                asm("v_cvt_pk_bf16_f32 %0, %1, %2" : "=v"(pk3) : "v"(h2), "v"(h3));
            }
            // ---- A-frag for GEMM2 K-chunk hc: ha[j] = H[sample l16][hc*32+q*8+j]
            int4 hw = make_int4((int)pk0, (int)pk1, (int)pk2, (int)pk3);
            short8 ha = *(short8*)&hw;
#pragma unroll
            for (int n = 0; n < 4; ++n) {
                int orow = n * 16 + l16;  // W2 row = o index
                short8 wb = *(const short8*)&sW2[orow * 256 + ((hc * 4 + q) ^ sx) * 8];
                oacc[n] = __builtin_amdgcn_mfma_f32_16x16x32_bf16(ha, wb, oacc[n], 0, 0, 0);
            }
        }
        // ---- epilogue: out = (H @ W2^T + b2) * e^s   (b2 folded into init)
#pragma unroll
        for (int n = 0; n < 4; ++n) {
#pragma unroll
            for (int reg = 0; reg < 4; ++reg) {
                out[(m0 + wave * 16 + q * 4 + reg) * 64 + n * 16 + l16] =
                    oacc[n][reg] * sc[reg];
            }
        }
    }
}

extern "C" void kernel_launch(void* const* d_in, const int* in_sizes, int n_in,
                              void* d_out, int out_size, void* d_ws, size_t ws_size,
                              hipStream_t stream) {
    const float* x  = (const float*)d_in[0];
    const float* r  = (const float*)d_in[1];
    const float* W1 = (const float*)d_in[2];
    const float* b1 = (const float*)d_in[3];
    const float* W2 = (const float*)d_in[4];
    const float* b2 = (const float*)d_in[5];
    float* out = (float*)d_out;
    int B = in_sizes[0] / 64;  // 262144

    int tiles = B / 128;           // 2048 tiles of 128 samples
    int blocks = 512;              // 2 per CU
    int tpb = tiles / blocks;      // 4

    fused_k<<<blocks, 512, 0, stream>>>(x, r, W1, b1, W2, b2, out, tpb);
}

// Round 11
// 137.267 us; speedup vs baseline: 1.0244x; 1.0237x over previous
//
#include <hip/hip_runtime.h>

typedef __attribute__((ext_vector_type(8))) short short8;
typedef __attribute__((ext_vector_type(4))) float floatx4;
typedef __attribute__((ext_vector_type(2))) unsigned uint2e;

static __device__ __forceinline__ unsigned short f2bf(float f) {
    unsigned u = __float_as_uint(f);
    u += 0x7FFFu + ((u >> 16) & 1u);
    return (unsigned short)(u >> 16);
}

// VALU butterfly reductions via gfx950 permlane-swap BUILTINS (no DS pipe,
// ~8cy vs ~120cy ds_bpermute). With vdst_old = vsrc_old = x, the result
// pair {p.x, p.y} satisfies p.x[i] + p.y[i] == x[i] + x[i^16] (resp ^32).
// R10 LESSON: the hand-asm version ("+v"(a), "+v"(b) with a==b==x) let the
// register allocator COALESCE a and b into one VGPR -> self-swap ->
// 2*x[i^16] -> Newton diverged -> NaN. The builtin owns the two-register
// contract, so this cannot happen.
static __device__ __forceinline__ float pl16_sum(float x) {
    unsigned u = __float_as_uint(x);
    uint2e p = __builtin_amdgcn_permlane16_swap(u, u, false, false);
    return __uint_as_float(p.x) + __uint_as_float(p.y);
}
static __device__ __forceinline__ float pl32_sum(float x) {
    unsigned u = __float_as_uint(x);
    uint2e p = __builtin_amdgcn_permlane32_swap(u, u, false, false);
    return __uint_as_float(p.x) + __uint_as_float(p.y);
}
static __device__ __forceinline__ int pl16_or(int x) {
    uint2e p = __builtin_amdgcn_permlane16_swap((unsigned)x, (unsigned)x, false, false);
    return (int)(p.x | p.y);
}
static __device__ __forceinline__ int pl32_or(int x) {
    uint2e p = __builtin_amdgcn_permlane32_swap((unsigned)x, (unsigned)x, false, false);
    return (int)(p.x | p.y);
}

// ================= single fused kernel =================
// R11 = R10's DS-pipe-diet hypothesis, correctly implemented. Evidence
// base: R8 (8 waves/SIMD == 4) + R9 (VALU cuts null) localize the
// bottleneck to the per-CU-shared LDS pipe: ~110 DS ops/wave-tile
// (64 weight b128 + 16 sB1 + ~30 shuffle) ~= 80% DS busy, AND two serial
// ~120cy shuffles inside every Newton iteration. Fix: all quad
// reductions via permlane{16,32}_swap (VALU) -- the Newton loop has
// ZERO DS ops and ~240cy less serial latency per iteration.
// Solver = R7 log-Newton (Halley measured-neutral in R9). Keeps R9's
// cvt_pk a0/a1 pack and next-tile x prefetch.
// Geometry = R7 (best measured): 512 threads, LDS 66560B -> 2 blocks/CU.
// __launch_bounds__(512,2) = the only bound giving full regs (R3/R5).
//
// R7 recap (unchanged): GEMM1 swapped (mfma(wb,a)) so each lane holds H
// for its own sample; h-dimension globally permuted at staging (slot(h)
// = (2*(h>>5)+((h>>2)&1))*16 + ((h>>3)&3)*4 + (h&3) applied to W1 rows
// + b1; W2 read logical) so packed GEMM1 outputs concatenate into
// EXACTLY the K=32 GEMM2 A-frag; zero LDS H traffic, no __syncthreads
// in tile loop; b1 in MFMA C-init, b2 in oacc init.
// Lane mapping (R2): lane (q,l16) of wave w owns sample w*16+l16, coord
// chunks {8q..8q+7} / {32+8q..+7}; e^s fans out with 4 __shfl.
// Early break __all(|v-1|<1e-5); the -1 of F applies ONCE, post-reduction.
__global__ __launch_bounds__(512, 2) void fused_k(const float* __restrict__ x,
                                                  const float* __restrict__ r,
                                                  const float* __restrict__ W1f,
                                                  const float* __restrict__ b1,
                                                  const float* __restrict__ W2f,
                                                  const float* __restrict__ b2,
                                                  float* __restrict__ out,
                                                  int tiles_per_block) {
    __shared__ unsigned short sW1[256 * 64];  // 32 KB, PERMUTED rows, swizzled
    __shared__ unsigned short sW2[64 * 256];  // 32 KB, logical-h order, swizzled
    __shared__ float sB1[256];                //  1 KB, b1 at permuted slots

    int tid = threadIdx.x;

    // ---- stage W1 [256x64] fp32 -> bf16, row-PERMUTED by pi, swizzled
    const float4* w1f4 = (const float4*)W1f;
#pragma unroll
    for (int c = 0; c < 4; ++c) {
        int g = tid + c * 512;
        int h = g >> 3, ch = g & 7;  // logical row, 8-elem chunk
        int prow = ((h >> 5) * 2 + ((h >> 2) & 1)) * 16 + ((h >> 3) & 3) * 4 + (h & 3);
        float4 lo = w1f4[2 * g], hi = w1f4[2 * g + 1];
        uint4 p;
        p.x = (unsigned)f2bf(lo.x) | ((unsigned)f2bf(lo.y) << 16);
        p.y = (unsigned)f2bf(lo.z) | ((unsigned)f2bf(lo.w) << 16);
        p.z = (unsigned)f2bf(hi.x) | ((unsigned)f2bf(hi.y) << 16);
        p.w = (unsigned)f2bf(hi.z) | ((unsigned)f2bf(hi.w) << 16);
        *(uint4*)&sW1[prow * 64 + (ch ^ (prow & 7)) * 8] = p;
    }
    // ---- stage W2 [64x256] fp32 -> bf16 swizzled (logical h order)
    const float4* w2f4 = (const float4*)W2f;
#pragma unroll
    for (int c = 0; c < 4; ++c) {
        int g = tid + c * 512;
        float4 lo = w2f4[2 * g], hi = w2f4[2 * g + 1];
        uint4 p;
        p.x = (unsigned)f2bf(lo.x) | ((unsigned)f2bf(lo.y) << 16);
        p.y = (unsigned)f2bf(lo.z) | ((unsigned)f2bf(lo.w) << 16);
        p.z = (unsigned)f2bf(hi.x) | ((unsigned)f2bf(hi.y) << 16);
        p.w = (unsigned)f2bf(hi.z) | ((unsigned)f2bf(hi.w) << 16);
        int row = g >> 5, ch = g & 31;
        *(uint4*)&sW2[row * 256 + (ch ^ (row & 7)) * 8] = p;
    }
    // ---- stage b1 at permuted slots
    if (tid < 256) {
        int h = tid;
        int prow = ((h >> 5) * 2 + ((h >> 2) & 1)) * 16 + ((h >> 3) & 3) * 4 + (h & 3);
        sB1[prow] = b1[h];
    }
    __syncthreads();

    int wave = tid >> 6, lane = tid & 63;
    int q = lane >> 4, l16 = lane & 15;
    int sx = l16 & 7;  // swizzle key for rows indexed by l16

    float bias2[4];
#pragma unroll
    for (int n = 0; n < 4; ++n) bias2[n] = b2[n * 16 + l16];

    // ---- per-thread rate chunks: coords {8q..8q+7} and {32+8q..+7}
    const float L2E2 = 2.8853900817779268f;  // 2*log2(e)
    float rl2[16];
    {
        const float4* r4 = (const float4*)r;
        float4 ra = r4[2 * q], rb = r4[2 * q + 1];
        float4 rc = r4[8 + 2 * q], rd = r4[8 + 2 * q + 1];
        rl2[0] = ra.x * L2E2; rl2[1] = ra.y * L2E2; rl2[2] = ra.z * L2E2; rl2[3] = ra.w * L2E2;
        rl2[4] = rb.x * L2E2; rl2[5] = rb.y * L2E2; rl2[6] = rb.z * L2E2; rl2[7] = rb.w * L2E2;
        rl2[8] = rc.x * L2E2; rl2[9] = rc.y * L2E2; rl2[10] = rc.z * L2E2; rl2[11] = rc.w * L2E2;
        rl2[12] = rd.x * L2E2; rl2[13] = rd.y * L2E2; rl2[14] = rd.z * L2E2; rl2[15] = rd.w * L2E2;
    }

    int myrow = wave * 16 + l16;  // 0..127
    size_t mb = (size_t)blockIdx.x * tiles_per_block * 128;
    const float4* xt = (const float4*)(x + (mb + myrow) * 64);  // tile 0, my row

    // ---- prefetch tile 0
    float4 va = xt[2 * q], vb = xt[2 * q + 1];
    float4 vc = xt[8 + 2 * q], vd = xt[8 + 2 * q + 1];

    for (int tt = 0; tt < tiles_per_block; ++tt) {
        size_t m0 = mb + (size_t)tt * 128;

        float xv[16];
        xv[0] = va.x; xv[1] = va.y; xv[2] = va.z; xv[3] = va.w;
        xv[4] = vb.x; xv[5] = vb.y; xv[6] = vb.z; xv[7] = vb.w;
        xv[8] = vc.x; xv[9] = vc.y; xv[10] = vc.z; xv[11] = vc.w;
        xv[12] = vd.x; xv[13] = vd.y; xv[14] = vd.z; xv[15] = vd.w;

        // ---- issue next tile's loads NOW (hide L3/HBM latency under solve+GEMM)
        {
            int nt = (tt + 1 < tiles_per_block) ? (tt + 1) : tt;
            const float4* xn = xt + (size_t)nt * 2048;  // 128 rows * 16 float4
            va = xn[2 * q]; vb = xn[2 * q + 1];
            vc = xn[8 + 2 * q]; vd = xn[8 + 2 * q + 1];
        }

        float x2[16], rx2[16];
        float sum0 = 0.f, sumr = 0.f;
        int nz = 0;
#pragma unroll
        for (int j = 0; j < 16; ++j) {
            x2[j] = xv[j] * xv[j];
            rx2[j] = rl2[j] * x2[j];
            sum0 += x2[j];
            sumr += rx2[j];
            nz |= (fabsf(xv[j]) > 1e-12f) ? 1 : 0;
        }
        // quad reduction (owners differ in lane bits 4,5) -- pure VALU
        sum0 = pl32_sum(pl16_sum(sum0));
        sumr = pl32_sum(pl16_sum(sumr));
        nz = pl32_or(pl16_or(nz));

        float s = 0.f;
        if (nz) {
            // init = log-Newton step from s=0
            s = __log2f(sum0) * sum0 * __builtin_amdgcn_rcpf(sumr);
#pragma unroll 1
            for (int it = 0; it < 10; ++it) {
                float ns = -s;
                float v = 0.f, dv = 0.f;
#pragma unroll
                for (int j = 0; j < 16; ++j) {
                    float e = __builtin_amdgcn_exp2f(ns * rl2[j]);
                    v = fmaf(e, x2[j], v);
                    dv = fmaf(e, rx2[j], dv);
                }
                v = pl32_sum(pl16_sum(v));
                dv = pl32_sum(pl16_sum(dv));
                if (__all(fabsf(v - 1.f) < 1e-5f)) break;
                // log-Newton in base 2: s += log2(v)*v/dv2
                s += __log2f(v) * v * __builtin_amdgcn_rcpf(dv);
            }
        }

        // ---- B-frags (GEMM1) from the solve: xs = x * 2^{-s*rl2/2}, packed
        float hs = -0.5f * s;
        unsigned pa[8];
#pragma unroll
        for (int j = 0; j < 8; ++j) {
            float ea = xv[2 * j] * __builtin_amdgcn_exp2f(hs * rl2[2 * j]);
            float eb = xv[2 * j + 1] * __builtin_amdgcn_exp2f(hs * rl2[2 * j + 1]);
            asm("v_cvt_pk_bf16_f32 %0, %1, %2" : "=v"(pa[j]) : "v"(ea), "v"(eb));
        }
        int4 w0 = make_int4((int)pa[0], (int)pa[1], (int)pa[2], (int)pa[3]);
        int4 w1 = make_int4((int)pa[4], (int)pa[5], (int)pa[6], (int)pa[7]);
        short8 a0 = *(short8*)&w0;
        short8 a1 = *(short8*)&w1;

        // e^s, fan out to the lanes that scale samples q*4+reg
        float es = __builtin_amdgcn_exp2f(s * 1.4426950408889634f);
        float sc[4];
#pragma unroll
        for (int reg = 0; reg < 4; ++reg) sc[reg] = __shfl(es, q * 4 + reg);

        floatx4 oacc[4];
#pragma unroll
        for (int n = 0; n < 4; ++n)
            oacc[n] = (floatx4){bias2[n], bias2[n], bias2[n], bias2[n]};

#pragma unroll
        for (int hc = 0; hc < 8; ++hc) {
            // ---- GEMM1 (swapped), subtile pair (2hc, 2hc+1):
            // acc[reg] = H[logical h = hc*32 + q*8 + p*4 + reg][sample l16]
            unsigned pk0, pk1, pk2, pk3;
            {
                int t = hc * 2;
                int row = t * 16 + l16;
                short8 wb0 = *(const short8*)&sW1[row * 64 + (q ^ sx) * 8];
                short8 wb1 = *(const short8*)&sW1[row * 64 + ((q + 4) ^ sx) * 8];
                const float4 bb = *(const float4*)&sB1[t * 16 + q * 4];
                floatx4 acc = (floatx4){bb.x, bb.y, bb.z, bb.w};
                acc = __builtin_amdgcn_mfma_f32_16x16x32_bf16(wb0, a0, acc, 0, 0, 0);
                acc = __builtin_amdgcn_mfma_f32_16x16x32_bf16(wb1, a1, acc, 0, 0, 0);
                float h0 = fmaxf(acc[0], 0.f), h1 = fmaxf(acc[1], 0.f);
                float h2 = fmaxf(acc[2], 0.f), h3 = fmaxf(acc[3], 0.f);
                asm("v_cvt_pk_bf16_f32 %0, %1, %2" : "=v"(pk0) : "v"(h0), "v"(h1));
                asm("v_cvt_pk_bf16_f32 %0, %1, %2" : "=v"(pk1) : "v"(h2), "v"(h3));
            }
            {
                int t = hc * 2 + 1;
                int row = t * 16 + l16;
                short8 wb0 = *(const short8*)&sW1[row * 64 + (q ^ sx) * 8];
                short8 wb1 = *(const short8*)&sW1[row * 64 + ((q + 4) ^ sx) * 8];
                const float4 bb = *(const float4*)&sB1[t * 16 + q * 4];
                floatx4 acc = (floatx4){bb.x, bb.y, bb.z, bb.w};
                acc = __builtin_amdgcn_mfma_f32_16x16x32_bf16(wb0, a0, acc, 0, 0, 0);
                acc = __builtin_amdgcn_mfma_f32_16x16x32_bf16(wb1, a1, acc, 0, 0, 0);
                float h0 = fmaxf(acc[0], 0.f), h1 = fmaxf(acc[1], 0.f);
                float h2 = fmaxf(acc[2], 0.f), h3 = fmaxf(acc[3], 0.f);
                asm("v_cvt_pk_bf16_f32 %0, %1, %2" : "=v"(pk2) : "v"(h0), "v"(h1));
                asm("v_cvt_pk_bf16_f32 %0, %1, %2" : "=v"(pk3) : "v"(h2), "v"(h3));
            }
            // ---- A-frag for GEMM2 K-chunk hc: ha[j] = H[sample l16][hc*32+q*8+j]
            int4 hw = make_int4((int)pk0, (int)pk1, (int)pk2, (int)pk3);
            short8 ha = *(short8*)&hw;
#pragma unroll
            for (int n = 0; n < 4; ++n) {
                int orow = n * 16 + l16;  // W2 row = o index
                short8 wb = *(const short8*)&sW2[orow * 256 + ((hc * 4 + q) ^ sx) * 8];
                oacc[n] = __builtin_amdgcn_mfma_f32_16x16x32_bf16(ha, wb, oacc[n], 0, 0, 0);
            }
        }
        // ---- epilogue: out = (H @ W2^T + b2) * e^s   (b2 folded into init)
#pragma unroll
        for (int n = 0; n < 4; ++n) {
#pragma unroll
            for (int reg = 0; reg < 4; ++reg) {
                out[(m0 + wave * 16 + q * 4 + reg) * 64 + n * 16 + l16] =
                    oacc[n][reg] * sc[reg];
            }
        }
    }
}

extern "C" void kernel_launch(void* const* d_in, const int* in_sizes, int n_in,
                              void* d_out, int out_size, void* d_ws, size_t ws_size,
                              hipStream_t stream) {
    const float* x  = (const float*)d_in[0];
    const float* r  = (const float*)d_in[1];
    const float* W1 = (const float*)d_in[2];
    const float* b1 = (const float*)d_in[3];
    const float* W2 = (const float*)d_in[4];
    const float* b2 = (const float*)d_in[5];
    float* out = (float*)d_out;
    int B = in_sizes[0] / 64;  // 262144

    int tiles = B / 128;           // 2048 tiles of 128 samples
    int blocks = 512;              // 2 per CU
    int tpb = tiles / blocks;      // 4

    fused_k<<<blocks, 512, 0, stream>>>(x, r, W1, b1, W2, b2, out, tpb);
}